// Round 3
// baseline (1014.905 us; speedup 1.0000x reference)
//
#include <hip/hip_runtime.h>

// Decoder layer: x -> rms -> QKV -> causal attn -> +x@wo -> rms -> SwiGLU -> +down
// B=2 S=2048 H=2048 NH=16 HD=128 FF=8192, fp32 I/O, bf16 MFMA compute.

#define HH 2048
#define FF 8192
#define BB 2
#define SS 2048
#define NHH 16
#define HDD 128
#define MM (BB * SS)  // 4096 rows

typedef __attribute__((ext_vector_type(8))) short short8;
typedef __attribute__((ext_vector_type(4))) short short4v;
typedef __attribute__((ext_vector_type(4))) float f32x4;

#define DEV __device__ __forceinline__

DEV short f2bf(float f) {  // RNE f32->bf16
  unsigned u = __builtin_bit_cast(unsigned, f);
  u += 0x7fffu + ((u >> 16) & 1u);
  return (short)(u >> 16);
}
DEV float bf2f(short s) {
  unsigned u = ((unsigned)(unsigned short)s) << 16;
  return __builtin_bit_cast(float, u);
}

// async global->LDS, 16B per lane; lds ptr must be wave-uniform, HW adds lane*16
#define GLL16(gp, lp)                                                    \
  __builtin_amdgcn_global_load_lds(                                      \
      (const __attribute__((address_space(1))) void*)(gp),               \
      (__attribute__((address_space(3))) void*)(lp), 16, 0, 0)

// ---------------- weight transpose + cast: W[K][N] f32 -> Wt[N][K] bf16 -----
__global__ __launch_bounds__(256) void transpose_cast(
    const float* __restrict__ W, short* __restrict__ Wt, int K, int N) {
  __shared__ float tile[32][33];
  int n0 = blockIdx.x * 32, k0 = blockIdx.y * 32;
  int tx = threadIdx.x & 31, ty = threadIdx.x >> 5;
#pragma unroll
  for (int i = 0; i < 32; i += 8)
    tile[ty + i][tx] = W[(long)(k0 + ty + i) * N + n0 + tx];
  __syncthreads();
#pragma unroll
  for (int i = 0; i < 32; i += 8)
    Wt[(long)(n0 + ty + i) * K + k0 + tx] = f2bf(tile[tx][ty + i]);
}

// ---------------- RMSNorm row kernel: f32 in -> bf16 out --------------------
__global__ __launch_bounds__(256) void rmsnorm_k(const float* __restrict__ x,
                                                 const float* __restrict__ g,
                                                 short* __restrict__ out) {
  int row = blockIdx.x;
  int t = threadIdx.x;
  const float* xr = x + (long)row * HH;
  f32x4 v0 = *(const f32x4*)(xr + t * 4);
  f32x4 v1 = *(const f32x4*)(xr + 1024 + t * 4);
  float ss = v0[0] * v0[0] + v0[1] * v0[1] + v0[2] * v0[2] + v0[3] * v0[3] +
             v1[0] * v1[0] + v1[1] * v1[1] + v1[2] * v1[2] + v1[3] * v1[3];
#pragma unroll
  for (int off = 1; off < 64; off <<= 1) ss += __shfl_xor(ss, off);
  __shared__ float red[4];
  if ((t & 63) == 0) red[t >> 6] = ss;
  __syncthreads();
  float tot = red[0] + red[1] + red[2] + red[3];
  float rs = rsqrtf(tot * (1.0f / HH) + 1e-6f);
  f32x4 g0 = *(const f32x4*)(g + t * 4);
  f32x4 g1 = *(const f32x4*)(g + 1024 + t * 4);
  short4v o0, o1;
#pragma unroll
  for (int e = 0; e < 4; ++e) {
    o0[e] = f2bf(v0[e] * rs * g0[e]);
    o1[e] = f2bf(v1[e] * rs * g1[e]);
  }
  *(short4v*)(out + (long)row * HH + t * 4) = o0;
  *(short4v*)(out + (long)row * HH + 1024 + t * 4) = o1;
}

// ---------------- bf16 MFMA GEMM (m97 128x128, 2-phase) ---------------------
// EPI: 0 plain bf16 [M][N]; 1 bf16 per-head [b,h,s,d]; 2 bf16 Vt [b,h,d,s];
//      3 f32 out = aux(f32)[M][N] + acc; 4 bf16 out = silu(aux bf16)*acc.
template <int EPI>
__global__ __launch_bounds__(256) void gemm_bt(const short* __restrict__ A,
                                               const short* __restrict__ Bt,
                                               int M, int N, int K,
                                               void* out, const void* aux) {
  __shared__ short As[128 * 64];
  __shared__ short Bs[128 * 64];
  int nbn = N >> 7;
  int nwg = gridDim.x;
  int bid = blockIdx.x;
  int qq = nwg >> 3, rr = nwg & 7;
  int xcd = bid & 7, lid = bid >> 3;
  int wg = (xcd < rr ? xcd * (qq + 1) : rr * (qq + 1) + (xcd - rr) * qq) + lid;
  int bm = wg / nbn, bn = wg % nbn;
  int t = threadIdx.x, w = t >> 6, lane = t & 63, lg = lane >> 4, c = lane & 15;
  int wr = w >> 1, wc = w & 1;
  const short* Abase = A + (long)bm * 128 * K;
  const short* Bbase = Bt + (long)bn * 128 * K;
  f32x4 acc[4][4] = {};
  int nk = K >> 6;
  for (int kt = 0; kt < nk; ++kt) {
    int k0 = kt << 6;
    __syncthreads();
#pragma unroll
    for (int i = 0; i < 4; ++i) {
      int idx = i * 256 + t;
      int row = idx >> 3, p = idx & 7;
      int col = k0 + ((p ^ (row & 7)) << 3);
      GLL16(Abase + (long)row * K + col, As + (i * 256 + w * 64) * 8);
      GLL16(Bbase + (long)row * K + col, Bs + (i * 256 + w * 64) * 8);
    }
    __syncthreads();
#pragma unroll
    for (int kk = 0; kk < 2; ++kk) {
      short8 af[4], bfr[4];
#pragma unroll
      for (int m = 0; m < 4; ++m) {
        int row = wr * 64 + m * 16 + c;
        af[m] = *(const short8*)(As + row * 64 + ((((kk << 2) | lg) ^ (row & 7)) << 3));
      }
#pragma unroll
      for (int n = 0; n < 4; ++n) {
        int row = wc * 64 + n * 16 + c;
        bfr[n] = *(const short8*)(Bs + row * 64 + ((((kk << 2) | lg) ^ (row & 7)) << 3));
      }
#pragma unroll
      for (int m = 0; m < 4; ++m)
#pragma unroll
        for (int n = 0; n < 4; ++n)
          acc[m][n] = __builtin_amdgcn_mfma_f32_16x16x32_bf16(af[m], bfr[n], acc[m][n], 0, 0, 0);
    }
  }
#pragma unroll
  for (int m = 0; m < 4; ++m) {
#pragma unroll
    for (int n = 0; n < 4; ++n) {
      int rL = wr * 64 + m * 16 + lg * 4;
      int cL = wc * 64 + n * 16 + c;
      long rg = (long)bm * 128 + rL;
      long cg = (long)bn * 128 + cL;
      if (EPI == 2) {
        int b = (int)(rg >> 11), s = (int)(rg & 2047);
        int head = (int)(cg >> 7), d = (int)(cg & 127);
        short4v pk;
#pragma unroll
        for (int j = 0; j < 4; ++j) pk[j] = f2bf(acc[m][n][j]);
        *(short4v*)((short*)out + ((long)(b * NHH + head) * HDD + d) * SS + s) = pk;
      } else {
#pragma unroll
        for (int j = 0; j < 4; ++j) {
          long r = rg + j;
          float v = acc[m][n][j];
          if (EPI == 0) {
            ((short*)out)[r * N + cg] = f2bf(v);
          } else if (EPI == 1) {
            int b = (int)(r >> 11), s = (int)(r & 2047);
            int head = (int)(cg >> 7), d = (int)(cg & 127);
            ((short*)out)[((long)(b * NHH + head) * SS + s) * HDD + d] = f2bf(v);
          } else if (EPI == 3) {
            ((float*)out)[r * N + cg] = ((const float*)aux)[r * N + cg] + v;
          } else if (EPI == 4) {
            float gv = bf2f(((const short*)aux)[r * N + cg]);
            float sg = gv / (1.0f + __expf(-gv));
            ((short*)out)[r * N + cg] = f2bf(sg * v);
          }
        }
      }
    }
  }
}

// ---------------- 256x256 8-phase GEMM (T2+T3+T4+T5) ------------------------
// 8 waves (2Mx4N), BK=64, wave output 128x64 (8x4 16x16x32 frags).
// LDS: 2 K-tile buffers x (A 256x64 + B 256x64) bf16 = 128 KiB.
// "Half-tiles" are per-wave-quadrant row sets so each phase's barrier frees
// exactly one stage-target region:
//   A-half mh = rows {wr*128 + mh*64 + [0,64)}   (LDS rho = wr*64 + u)
//   B-half nh = rows {wc*64  + nh*32 + [0,32)}   (LDS rho = wc*32 + v)
// Phase quads: P1(0,0) reads A0,B0; P2(0,1) reads B1; P3(1,1) reads A1;
// P4(1,0) register-only. Regs hold A-half across its 2 phases, B-halves
// across the tile. Stage issues (1 half/phase): P1: B1(t+1)->buf^1,
// P2: A0(t+2)->buf, P3: B0(t+2)->buf, P4: A1(t+2)->buf — each target was
// freed >=1 barrier earlier. vmcnt(6) once per tile (3 halves in flight);
// tails wrap stage tile index mod nk (dead data, keeps counts uniform).
template <int MH, int NH>
DEV void mfma_quad(f32x4 (&acc)[8][4], const short8 (&a)[4][2],
                   const short8 (&bb)[2][2]) {
  __builtin_amdgcn_s_setprio(1);
#pragma unroll
  for (int i = 0; i < 4; ++i)
#pragma unroll
    for (int n2 = 0; n2 < 2; ++n2)
#pragma unroll
      for (int kk = 0; kk < 2; ++kk)
        acc[MH * 4 + i][NH * 2 + n2] = __builtin_amdgcn_mfma_f32_16x16x32_bf16(
            a[i][kk], bb[n2][kk], acc[MH * 4 + i][NH * 2 + n2], 0, 0, 0);
  __builtin_amdgcn_s_setprio(0);
}

#define SBAR()                          \
  __builtin_amdgcn_sched_barrier(0);    \
  __builtin_amdgcn_s_barrier()
#define LGKM0()                                        \
  asm volatile("s_waitcnt lgkmcnt(0)" ::: "memory");   \
  __builtin_amdgcn_sched_barrier(0)

template <int EPI>
__global__ __launch_bounds__(512, 2) void gemm256(const short* __restrict__ A,
                                                  const short* __restrict__ Bt,
                                                  int M, int N, int K,
                                                  void* out, const void* aux) {
  __shared__ short As[2][2][128 * 64];
  __shared__ short Bs[2][2][128 * 64];
  int nbn = N >> 8;
  int nwg = gridDim.x;
  int bid = blockIdx.x;
  int qq = nwg >> 3, rr = nwg & 7;
  int xcd = bid & 7, lid = bid >> 3;
  int wg = (xcd < rr ? xcd * (qq + 1) : rr * (qq + 1) + (xcd - rr) * qq) + lid;
  int bm = wg / nbn, bn = wg % nbn;
  int tid = threadIdx.x, w = tid >> 6, lane = tid & 63, lg = lane >> 4, cl = lane & 15;
  int wr = w >> 2, wc = w & 3;
  const short* Abase = A + (long)bm * 256 * K;
  const short* Bbase = Bt + (long)bn * 256 * K;

  f32x4 acc[8][4] = {};
  short8 a[4][2], b0[2][2], b1[2][2];
  int nk = K >> 6;  // requires nk even and >= 2 (K=2048/8192 -> 32/128)

  auto stageA = [&](int kt, int cb, int mh) {
    int k0 = kt << 6;
#pragma unroll
    for (int q = 0; q < 2; ++q) {
      int sg = q * 512 + tid;
      int rho = sg >> 3, p = sg & 7;
      int grow = ((rho >> 6) << 7) + (mh << 6) + (rho & 63);
      GLL16(Abase + (long)grow * K + k0 + ((p ^ (rho & 7)) << 3),
            &As[cb][mh][(q * 512 + w * 64) * 8]);
    }
  };
  auto stageB = [&](int kt, int cb, int nh) {
    int k0 = kt << 6;
#pragma unroll
    for (int q = 0; q < 2; ++q) {
      int sg = q * 512 + tid;
      int rho = sg >> 3, p = sg & 7;
      int grow = ((rho >> 5) << 6) + (nh << 5) + (rho & 31);
      GLL16(Bbase + (long)grow * K + k0 + ((p ^ (rho & 7)) << 3),
            &Bs[cb][nh][(q * 512 + w * 64) * 8]);
    }
  };
  auto readA = [&](int cb, int mh) {
#pragma unroll
    for (int i = 0; i < 4; ++i)
#pragma unroll
      for (int kk = 0; kk < 2; ++kk) {
        int rho = wr * 64 + i * 16 + cl;
        int slot = kk * 4 + lg;
        a[i][kk] = *(const short8*)(&As[cb][mh][rho * 64 + ((slot ^ (rho & 7)) << 3)]);
      }
  };
  auto readB = [&](int cb, int nh, short8(&bb)[2][2]) {
#pragma unroll
    for (int n2 = 0; n2 < 2; ++n2)
#pragma unroll
      for (int kk = 0; kk < 2; ++kk) {
        int rho = wc * 32 + n2 * 16 + cl;
        int slot = kk * 4 + lg;
        bb[n2][kk] = *(const short8*)(&Bs[cb][nh][rho * 64 + ((slot ^ (rho & 7)) << 3)]);
      }
  };

  // prologue: tile0 fully + tile1 {A0,A1,B0}; B1(1) issues in t=0 P1.
  stageA(0, 0, 0); stageA(0, 0, 1); stageB(0, 0, 0); stageB(0, 0, 1);
  stageA(1, 1, 0); stageA(1, 1, 1); stageB(1, 1, 0);
  asm volatile("s_waitcnt vmcnt(6)" ::: "memory");
  SBAR();

  for (int t = 0; t < nk; ++t) {
    int c = t & 1, cn = c ^ 1;
    int t1 = t + 1 < nk ? t + 1 : t + 1 - nk;
    int t2 = t + 2 < nk ? t + 2 : t + 2 - nk;
    // ---- P1: quad (0,0); 12 ds_reads
    readA(c, 0);
    readB(c, 0, b0);
    stageB(t1, cn, 1);
    asm volatile("s_waitcnt lgkmcnt(8)" ::: "memory");
    SBAR();
    LGKM0();
    mfma_quad<0, 0>(acc, a, b0);
    SBAR();
    // ---- P2: quad (0,1); 4 ds_reads
    readB(c, 1, b1);
    stageA(t2, c, 0);
    SBAR();
    LGKM0();
    mfma_quad<0, 1>(acc, a, b1);
    SBAR();
    // ---- P3: quad (1,1); 8 ds_reads
    readA(c, 1);
    stageB(t2, c, 0);
    SBAR();
    LGKM0();
    mfma_quad<1, 1>(acc, a, b1);
    SBAR();
    // ---- P4: quad (1,0); register-only, counted vmcnt once per K-tile
    stageA(t2, c, 1);
    asm volatile("s_waitcnt vmcnt(6)" ::: "memory");
    SBAR();
    mfma_quad<1, 0>(acc, a, b0);
    SBAR();
  }
  asm volatile("s_waitcnt vmcnt(0)" ::: "memory");

  // epilogue
#pragma unroll
  for (int m = 0; m < 8; ++m) {
#pragma unroll
    for (int n = 0; n < 4; ++n) {
      long rgb = (long)bm * 256 + wr * 128 + m * 16 + lg * 4;
      long cg = (long)bn * 256 + wc * 64 + n * 16 + cl;
#pragma unroll
      for (int j = 0; j < 4; ++j) {
        long r = rgb + j;
        float v = acc[m][n][j];
        if (EPI == 0) {
          ((short*)out)[r * N + cg] = f2bf(v);
        } else if (EPI == 3) {
          ((float*)out)[r * N + cg] = ((const float*)aux)[r * N + cg] + v;
        } else if (EPI == 4) {
          float gv = bf2f(((const short*)aux)[r * N + cg]);
          float sg = gv / (1.0f + __expf(-gv));
          ((short*)out)[r * N + cg] = f2bf(sg * v);
        }
      }
    }
  }
}

// ---------------- causal flash attention -----------------------------------
__global__ __launch_bounds__(512) void attn_k(const short* __restrict__ Qh,
                                              const short* __restrict__ Kh,
                                              const short* __restrict__ Vt,
                                              short* __restrict__ Ob) {
  __shared__ short Qs[128 * 128];
  __shared__ short Ks[128 * 128];
  __shared__ short Vs[128 * 128];
  __shared__ short Ps[128 * 128];
  int qt = blockIdx.x, bh = blockIdx.y;
  int t = threadIdx.x, w = t >> 6, lane = t & 63, lg = lane >> 4, c = lane & 15;
  int q0 = qt << 7;
  const short* Qb = Qh + (long)bh * SS * HDD;
  const short* Kb = Kh + (long)bh * SS * HDD;
  const short* Vb = Vt + (long)bh * HDD * SS;
#pragma unroll
  for (int i = 0; i < 4; ++i) {
    int idx = i * 512 + t;
    int row = idx >> 4, p = idx & 15;
    int col = (p ^ (row & 7)) << 3;
    GLL16(Qb + (long)(q0 + row) * HDD + col, Qs + (i * 512 + w * 64) * 8);
  }
  __syncthreads();
  short8 qf[4];
  int qrow = w * 16 + c;
#pragma unroll
  for (int kk = 0; kk < 4; ++kk)
    qf[kk] = *(const short8*)(Qs + qrow * 128 + ((((kk << 2) | lg) ^ (qrow & 7)) << 3));

  f32x4 o[8] = {};
  float mrun[4] = {-1e30f, -1e30f, -1e30f, -1e30f};
  float lrun[4] = {0.f, 0.f, 0.f, 0.f};
  const float scale = 0.08838834764831845f;
  for (int kt = 0; kt <= qt; ++kt) {
    int kv0 = kt << 7;
    __syncthreads();
#pragma unroll
    for (int i = 0; i < 4; ++i) {
      int idx = i * 512 + t;
      int row = idx >> 4, p = idx & 15;
      int col = (p ^ (row & 7)) << 3;
      GLL16(Kb + (long)(kv0 + row) * HDD + col, Ks + (i * 512 + w * 64) * 8);
      GLL16(Vb + (long)row * SS + kv0 + col, Vs + (i * 512 + w * 64) * 8);
    }
    __syncthreads();
    f32x4 sv[8];
#pragma unroll
    for (int n = 0; n < 8; ++n) {
      f32x4 acc = {};
#pragma unroll
      for (int kk = 0; kk < 4; ++kk) {
        int krow = n * 16 + c;
        short8 kf = *(const short8*)(Ks + krow * 128 + ((((kk << 2) | lg) ^ (krow & 7)) << 3));
        acc = __builtin_amdgcn_mfma_f32_16x16x32_bf16(qf[kk], kf, acc, 0, 0, 0);
      }
      sv[n] = acc;
    }
    int qg = q0 + w * 16 + lg * 4;
    if (kt == qt) {
#pragma unroll
      for (int n = 0; n < 8; ++n) {
        int col = kv0 + n * 16 + c;
#pragma unroll
        for (int j = 0; j < 4; ++j) {
          float xv = sv[n][j] * scale;
          sv[n][j] = (col > qg + j) ? -1e30f : xv;
        }
      }
    } else {
#pragma unroll
      for (int n = 0; n < 8; ++n)
#pragma unroll
        for (int j = 0; j < 4; ++j) sv[n][j] *= scale;
    }
    float alpha[4];
#pragma unroll
    for (int j = 0; j < 4; ++j) {
      float mx = sv[0][j];
#pragma unroll
      for (int n = 1; n < 8; ++n) mx = fmaxf(mx, sv[n][j]);
      mx = fmaxf(mx, __shfl_xor(mx, 1));
      mx = fmaxf(mx, __shfl_xor(mx, 2));
      mx = fmaxf(mx, __shfl_xor(mx, 4));
      mx = fmaxf(mx, __shfl_xor(mx, 8));
      float mnew = fmaxf(mrun[j], mx);
      alpha[j] = __expf(mrun[j] - mnew);
      mrun[j] = mnew;
    }
    float rsum[4] = {0.f, 0.f, 0.f, 0.f};
#pragma unroll
    for (int n = 0; n < 8; ++n)
#pragma unroll
      for (int j = 0; j < 4; ++j) {
        float p = __expf(sv[n][j] - mrun[j]);
        sv[n][j] = p;
        rsum[j] += p;
      }
#pragma unroll
    for (int j = 0; j < 4; ++j) {
      rsum[j] += __shfl_xor(rsum[j], 1);
      rsum[j] += __shfl_xor(rsum[j], 2);
      rsum[j] += __shfl_xor(rsum[j], 4);
      rsum[j] += __shfl_xor(rsum[j], 8);
      lrun[j] = lrun[j] * alpha[j] + rsum[j];
    }
#pragma unroll
    for (int n = 0; n < 8; ++n)
#pragma unroll
      for (int j = 0; j < 4; ++j) o[n][j] *= alpha[j];
#pragma unroll
    for (int n = 0; n < 8; ++n)
#pragma unroll
      for (int j = 0; j < 4; ++j) {
        int row = w * 16 + lg * 4 + j;
        int slot = (2 * n + (c >> 3)) ^ (row & 7);
        Ps[row * 128 + slot * 8 + (c & 7)] = f2bf(sv[n][j]);
      }
    __syncthreads();
    short8 pf[4];
    int prow = w * 16 + c;
#pragma unroll
    for (int kk = 0; kk < 4; ++kk)
      pf[kk] = *(const short8*)(Ps + prow * 128 + ((((kk << 2) | lg) ^ (prow & 7)) << 3));
#pragma unroll
    for (int n = 0; n < 8; ++n) {
#pragma unroll
      for (int kk = 0; kk < 4; ++kk) {
        int vrow = n * 16 + c;
        short8 vf = *(const short8*)(Vs + vrow * 128 + ((((kk << 2) | lg) ^ (vrow & 7)) << 3));
        o[n] = __builtin_amdgcn_mfma_f32_16x16x32_bf16(pf[kk], vf, o[n], 0, 0, 0);
      }
    }
  }
  int head = bh & (NHH - 1), b = bh >> 4;
#pragma unroll
  for (int j = 0; j < 4; ++j) {
    float inv = 1.0f / lrun[j];
    int s = q0 + w * 16 + lg * 4 + j;
#pragma unroll
    for (int n = 0; n < 8; ++n) {
      int hcol = head * 128 + n * 16 + c;
      Ob[((long)(b * SS + s)) * HH + hcol] = f2bf(o[n][j] * inv);
    }
  }
}

// ---------------------------------------------------------------------------
extern "C" void kernel_launch(void* const* d_in, const int* in_sizes, int n_in,
                              void* d_out, int out_size, void* d_ws, size_t ws_size,
                              hipStream_t stream) {
  (void)in_sizes; (void)n_in; (void)out_size;
  const float* x     = (const float*)d_in[0];
  const float* wq    = (const float*)d_in[2];
  const float* wk    = (const float*)d_in[3];
  const float* wv    = (const float*)d_in[4];
  const float* wo    = (const float*)d_in[5];
  const float* wgt   = (const float*)d_in[6];
  const float* wup   = (const float*)d_in[7];
  const float* wdn   = (const float*)d_in[8];
  const float* gin   = (const float*)d_in[9];
  const float* gpost = (const float*)d_in[10];
  float* out = (float*)d_out;

  const size_t R0 = 0;
  const size_t R1 = (size_t)32 << 20;
  const size_t R2 = (size_t)48 << 20;
  const size_t R3 = (size_t)112 << 20;
  const size_t NEED = (size_t)176 << 20;
  if (ws_size < NEED) return;

  short* wtq = (short*)((char*)d_ws + R0);
  short* wtk = wtq + (size_t)HH * HH;
  short* wtv = wtk + (size_t)HH * HH;
  short* wto = wtv + (size_t)HH * HH;
  short* wtd = (short*)((char*)d_ws + R0);
  short* hb  = (short*)((char*)d_ws + R1);
  short* h2  = hb;
  short* qh  = (short*)((char*)d_ws + R2);
  short* kh  = qh + (size_t)MM * HH;
  short* vt  = kh + (size_t)MM * HH;
  short* ab  = vt + (size_t)MM * HH;
  short* wtg = (short*)((char*)d_ws + R2);
  short* wtu = wtg + (size_t)HH * FF;
  short* gateb = (short*)((char*)d_ws + R3);

  dim3 b256(256, 1, 1);
  transpose_cast<<<dim3(HH / 32, HH / 32), b256, 0, stream>>>(wq, wtq, HH, HH);
  transpose_cast<<<dim3(HH / 32, HH / 32), b256, 0, stream>>>(wk, wtk, HH, HH);
  transpose_cast<<<dim3(HH / 32, HH / 32), b256, 0, stream>>>(wv, wtv, HH, HH);
  transpose_cast<<<dim3(HH / 32, HH / 32), b256, 0, stream>>>(wo, wto, HH, HH);

  rmsnorm_k<<<dim3(MM), b256, 0, stream>>>(x, gin, hb);

  dim3 gH((MM / 128) * (HH / 128), 1, 1);
  gemm_bt<1><<<gH, b256, 0, stream>>>(hb, wtq, MM, HH, HH, qh, nullptr);
  gemm_bt<1><<<gH, b256, 0, stream>>>(hb, wtk, MM, HH, HH, kh, nullptr);
  gemm_bt<2><<<gH, b256, 0, stream>>>(hb, wtv, MM, HH, HH, vt, nullptr);

  attn_k<<<dim3(SS / 128, BB * NHH), dim3(512, 1, 1), 0, stream>>>(qh, kh, vt, ab);

  gemm_bt<3><<<gH, b256, 0, stream>>>(ab, wto, MM, HH, HH, out, x);

  transpose_cast<<<dim3(FF / 32, HH / 32), b256, 0, stream>>>(wgt, wtg, HH, FF);
  transpose_cast<<<dim3(FF / 32, HH / 32), b256, 0, stream>>>(wup, wtu, HH, FF);
  transpose_cast<<<dim3(HH / 32, FF / 32), b256, 0, stream>>>(wdn, wtd, FF, HH);

  rmsnorm_k<<<dim3(MM), b256, 0, stream>>>(out, gpost, h2);

  dim3 b512(512, 1, 1);
  dim3 gF256((MM / 256) * (FF / 256), 1, 1);  // 512 WGs
  dim3 gH256((MM / 256) * (HH / 256), 1, 1);  // 128 WGs
  gemm256<0><<<gF256, b512, 0, stream>>>(h2, wtg, MM, FF, HH, gateb, nullptr);
  gemm256<4><<<gF256, b512, 0, stream>>>(h2, wtu, MM, FF, HH, gateb, gateb);
  gemm256<3><<<gH256, b512, 0, stream>>>(gateb, wtd, MM, HH, FF, out, out);
}

// Round 4
// 929.676 us; speedup vs baseline: 1.0917x; 1.0917x over previous
//
#include <hip/hip_runtime.h>

// Decoder layer: x -> rms -> QKV -> causal attn -> +x@wo -> rms -> SwiGLU -> +down
// B=2 S=2048 H=2048 NH=16 HD=128 FF=8192, fp32 I/O, bf16 MFMA compute.

#define HH 2048
#define FF 8192
#define BB 2
#define SS 2048
#define NHH 16
#define HDD 128
#define MM (BB * SS)  // 4096 rows

typedef __attribute__((ext_vector_type(8))) short short8;
typedef __attribute__((ext_vector_type(4))) short short4v;
typedef __attribute__((ext_vector_type(4))) float f32x4;

#define DEV __device__ __forceinline__

DEV short f2bf(float f) {  // RNE f32->bf16
  unsigned u = __builtin_bit_cast(unsigned, f);
  u += 0x7fffu + ((u >> 16) & 1u);
  return (short)(u >> 16);
}
DEV float bf2f(short s) {
  unsigned u = ((unsigned)(unsigned short)s) << 16;
  return __builtin_bit_cast(float, u);
}

// async global->LDS, 16B per lane; lds ptr must be wave-uniform, HW adds lane*16
#define GLL16(gp, lp)                                                    \
  __builtin_amdgcn_global_load_lds(                                      \
      (const __attribute__((address_space(1))) void*)(gp),               \
      (__attribute__((address_space(3))) void*)(lp), 16, 0, 0)

// ---------------- weight transpose + cast: W[K][N] f32 -> Wt[N][K] bf16 -----
__global__ __launch_bounds__(256) void transpose_cast(
    const float* __restrict__ W, short* __restrict__ Wt, int K, int N) {
  __shared__ float tile[32][33];
  int n0 = blockIdx.x * 32, k0 = blockIdx.y * 32;
  int tx = threadIdx.x & 31, ty = threadIdx.x >> 5;
#pragma unroll
  for (int i = 0; i < 32; i += 8)
    tile[ty + i][tx] = W[(long)(k0 + ty + i) * N + n0 + tx];
  __syncthreads();
#pragma unroll
  for (int i = 0; i < 32; i += 8)
    Wt[(long)(n0 + ty + i) * K + k0 + tx] = f2bf(tile[tx][ty + i]);
}

// ---------------- RMSNorm row kernel: f32 in -> bf16 out --------------------
__global__ __launch_bounds__(256) void rmsnorm_k(const float* __restrict__ x,
                                                 const float* __restrict__ g,
                                                 short* __restrict__ out) {
  int row = blockIdx.x;
  int t = threadIdx.x;
  const float* xr = x + (long)row * HH;
  f32x4 v0 = *(const f32x4*)(xr + t * 4);
  f32x4 v1 = *(const f32x4*)(xr + 1024 + t * 4);
  float ss = v0[0] * v0[0] + v0[1] * v0[1] + v0[2] * v0[2] + v0[3] * v0[3] +
             v1[0] * v1[0] + v1[1] * v1[1] + v1[2] * v1[2] + v1[3] * v1[3];
#pragma unroll
  for (int off = 1; off < 64; off <<= 1) ss += __shfl_xor(ss, off);
  __shared__ float red[4];
  if ((t & 63) == 0) red[t >> 6] = ss;
  __syncthreads();
  float tot = red[0] + red[1] + red[2] + red[3];
  float rs = rsqrtf(tot * (1.0f / HH) + 1e-6f);
  f32x4 g0 = *(const f32x4*)(g + t * 4);
  f32x4 g1 = *(const f32x4*)(g + 1024 + t * 4);
  short4v o0, o1;
#pragma unroll
  for (int e = 0; e < 4; ++e) {
    o0[e] = f2bf(v0[e] * rs * g0[e]);
    o1[e] = f2bf(v1[e] * rs * g1[e]);
  }
  *(short4v*)(out + (long)row * HH + t * 4) = o0;
  *(short4v*)(out + (long)row * HH + 1024 + t * 4) = o1;
}

// ---------------- bf16 MFMA GEMM (m97 128x128, 2-phase) ---------------------
// EPI: 0 plain bf16 [M][N]; 1 bf16 per-head [b,h,s,d]; 2 bf16 Vt [b,h,d,s];
//      3 f32 out = aux(f32)[M][N] + acc; 4 bf16 out = silu(aux bf16)*acc.
template <int EPI>
__global__ __launch_bounds__(256) void gemm_bt(const short* __restrict__ A,
                                               const short* __restrict__ Bt,
                                               int M, int N, int K,
                                               void* out, const void* aux) {
  __shared__ short As[128 * 64];
  __shared__ short Bs[128 * 64];
  int nbn = N >> 7;
  int nwg = gridDim.x;
  int bid = blockIdx.x;
  int qq = nwg >> 3, rr = nwg & 7;
  int xcd = bid & 7, lid = bid >> 3;
  int wg = (xcd < rr ? xcd * (qq + 1) : rr * (qq + 1) + (xcd - rr) * qq) + lid;
  int bm = wg / nbn, bn = wg % nbn;
  int t = threadIdx.x, w = t >> 6, lane = t & 63, lg = lane >> 4, c = lane & 15;
  int wr = w >> 1, wc = w & 1;
  const short* Abase = A + (long)bm * 128 * K;
  const short* Bbase = Bt + (long)bn * 128 * K;
  f32x4 acc[4][4] = {};
  int nk = K >> 6;
  for (int kt = 0; kt < nk; ++kt) {
    int k0 = kt << 6;
    __syncthreads();
#pragma unroll
    for (int i = 0; i < 4; ++i) {
      int idx = i * 256 + t;
      int row = idx >> 3, p = idx & 7;
      int col = k0 + ((p ^ (row & 7)) << 3);
      GLL16(Abase + (long)row * K + col, As + (i * 256 + w * 64) * 8);
      GLL16(Bbase + (long)row * K + col, Bs + (i * 256 + w * 64) * 8);
    }
    __syncthreads();
#pragma unroll
    for (int kk = 0; kk < 2; ++kk) {
      short8 af[4], bfr[4];
#pragma unroll
      for (int m = 0; m < 4; ++m) {
        int row = wr * 64 + m * 16 + c;
        af[m] = *(const short8*)(As + row * 64 + ((((kk << 2) | lg) ^ (row & 7)) << 3));
      }
#pragma unroll
      for (int n = 0; n < 4; ++n) {
        int row = wc * 64 + n * 16 + c;
        bfr[n] = *(const short8*)(Bs + row * 64 + ((((kk << 2) | lg) ^ (row & 7)) << 3));
      }
#pragma unroll
      for (int m = 0; m < 4; ++m)
#pragma unroll
        for (int n = 0; n < 4; ++n)
          acc[m][n] = __builtin_amdgcn_mfma_f32_16x16x32_bf16(af[m], bfr[n], acc[m][n], 0, 0, 0);
    }
  }
#pragma unroll
  for (int m = 0; m < 4; ++m) {
#pragma unroll
    for (int n = 0; n < 4; ++n) {
      int rL = wr * 64 + m * 16 + lg * 4;
      int cL = wc * 64 + n * 16 + c;
      long rg = (long)bm * 128 + rL;
      long cg = (long)bn * 128 + cL;
      if (EPI == 2) {
        int b = (int)(rg >> 11), s = (int)(rg & 2047);
        int head = (int)(cg >> 7), d = (int)(cg & 127);
        short4v pk;
#pragma unroll
        for (int j = 0; j < 4; ++j) pk[j] = f2bf(acc[m][n][j]);
        *(short4v*)((short*)out + ((long)(b * NHH + head) * HDD + d) * SS + s) = pk;
      } else {
#pragma unroll
        for (int j = 0; j < 4; ++j) {
          long r = rg + j;
          float v = acc[m][n][j];
          if (EPI == 0) {
            ((short*)out)[r * N + cg] = f2bf(v);
          } else if (EPI == 1) {
            int b = (int)(r >> 11), s = (int)(r & 2047);
            int head = (int)(cg >> 7), d = (int)(cg & 127);
            ((short*)out)[((long)(b * NHH + head) * SS + s) * HDD + d] = f2bf(v);
          } else if (EPI == 3) {
            ((float*)out)[r * N + cg] = ((const float*)aux)[r * N + cg] + v;
          } else if (EPI == 4) {
            float gv = bf2f(((const short*)aux)[r * N + cg]);
            float sg = gv / (1.0f + __expf(-gv));
            ((short*)out)[r * N + cg] = f2bf(sg * v);
          }
        }
      }
    }
  }
}

// ---------------- 256x256 8-phase GEMM (T2+T3+T4+T5) ------------------------
// Same pipeline invariants as validated R3 (stage targets freed >=1 barrier
// before overwrite; vmcnt(6) once per K-tile; tails wrap mod nk).
// R4 fixes: kk-OUTER MFMA order (no back-to-back same-acc dependency),
// compiler-managed lgkm waits (no forced drains), loop-invariant address
// precompute for ds_reads and stage sources.
template <int MH, int NHF>
DEV void mfma_quad(f32x4 (&acc)[8][4], const short8 (&a)[4][2],
                   const short8 (&bb)[2][2]) {
  __builtin_amdgcn_s_setprio(1);
#pragma unroll
  for (int kk = 0; kk < 2; ++kk)
#pragma unroll
    for (int i = 0; i < 4; ++i)
#pragma unroll
      for (int n2 = 0; n2 < 2; ++n2)
        acc[MH * 4 + i][NHF * 2 + n2] = __builtin_amdgcn_mfma_f32_16x16x32_bf16(
            a[i][kk], bb[n2][kk], acc[MH * 4 + i][NHF * 2 + n2], 0, 0, 0);
  __builtin_amdgcn_s_setprio(0);
}

#define SBAR()                          \
  __builtin_amdgcn_sched_barrier(0);    \
  __builtin_amdgcn_s_barrier()

template <int EPI>
__global__ __launch_bounds__(512, 2) void gemm256(const short* __restrict__ A,
                                                  const short* __restrict__ Bt,
                                                  int M, int N, int K,
                                                  void* out, const void* aux) {
  __shared__ short As[2][2][128 * 64];
  __shared__ short Bs[2][2][128 * 64];
  int nbn = N >> 8;
  int nwg = gridDim.x;
  int bid = blockIdx.x;
  int qq = nwg >> 3, rr = nwg & 7;
  int xcd = bid & 7, lid = bid >> 3;
  int wg = (xcd < rr ? xcd * (qq + 1) : rr * (qq + 1) + (xcd - rr) * qq) + lid;
  int bm = wg / nbn, bn = wg % nbn;
  int tid = threadIdx.x, w = tid >> 6, lane = tid & 63, lg = lane >> 4, cl = lane & 15;
  int wr = w >> 2, wc = w & 3;
  const short* Abase = A + (long)bm * 256 * K;
  const short* Bbase = Bt + (long)bn * 256 * K;

  f32x4 acc[8][4] = {};
  short8 a[4][2], b0[2][2], b1[2][2];
  int nk = K >> 6;  // nk even, >= 2 (K=2048/8192 -> 32/128)

  // ---- loop-invariant LDS read offsets (elements) ----
  int offA[4][2], offB[2][2];
#pragma unroll
  for (int i = 0; i < 4; ++i)
#pragma unroll
    for (int kk = 0; kk < 2; ++kk) {
      int rho = wr * 64 + i * 16 + cl;
      offA[i][kk] = rho * 64 + ((((kk << 2) | lg) ^ (rho & 7)) << 3);
    }
#pragma unroll
  for (int n2 = 0; n2 < 2; ++n2)
#pragma unroll
    for (int kk = 0; kk < 2; ++kk) {
      int rho = wc * 32 + n2 * 16 + cl;
      offB[n2][kk] = rho * 64 + ((((kk << 2) | lg) ^ (rho & 7)) << 3);
    }

  // ---- loop-invariant stage source pointers (add k0 per call) ----
  const short* srcA[2][2];  // [mh][q]
  const short* srcB[2][2];  // [nh][q]
#pragma unroll
  for (int q = 0; q < 2; ++q) {
    int sg = q * 512 + tid;
    int rho = sg >> 3, p = sg & 7;
    int swz = (p ^ (rho & 7)) << 3;
#pragma unroll
    for (int mh = 0; mh < 2; ++mh) {
      int growA = ((rho >> 6) << 7) + (mh << 6) + (rho & 63);
      srcA[mh][q] = Abase + (long)growA * K + swz;
      int growB = ((rho >> 5) << 6) + (mh << 5) + (rho & 31);
      srcB[mh][q] = Bbase + (long)growB * K + swz;
    }
  }
  auto stageA = [&](int kt, int cb, int mh) {
    int k0 = kt << 6;
    GLL16(srcA[mh][0] + k0, &As[cb][mh][(w * 64) * 8]);
    GLL16(srcA[mh][1] + k0, &As[cb][mh][(512 + w * 64) * 8]);
  };
  auto stageB = [&](int kt, int cb, int nh) {
    int k0 = kt << 6;
    GLL16(srcB[nh][0] + k0, &Bs[cb][nh][(w * 64) * 8]);
    GLL16(srcB[nh][1] + k0, &Bs[cb][nh][(512 + w * 64) * 8]);
  };
  auto readA = [&](int cb, int mh) {
#pragma unroll
    for (int i = 0; i < 4; ++i)
#pragma unroll
      for (int kk = 0; kk < 2; ++kk)
        a[i][kk] = *(const short8*)(&As[cb][mh][offA[i][kk]]);
  };
  auto readB = [&](int cb, int nh, short8(&bb)[2][2]) {
#pragma unroll
    for (int n2 = 0; n2 < 2; ++n2)
#pragma unroll
      for (int kk = 0; kk < 2; ++kk)
        bb[n2][kk] = *(const short8*)(&Bs[cb][nh][offB[n2][kk]]);
  };

  // prologue: tile0 fully + tile1 {A0,A1,B0}; B1(1) issues in t=0 P1.
  stageA(0, 0, 0); stageA(0, 0, 1); stageB(0, 0, 0); stageB(0, 0, 1);
  stageA(1, 1, 0); stageA(1, 1, 1); stageB(1, 1, 0);
  asm volatile("s_waitcnt vmcnt(6)" ::: "memory");
  SBAR();

  for (int t = 0; t < nk; ++t) {
    int c = t & 1, cn = c ^ 1;
    int t1 = t + 1 < nk ? t + 1 : t + 1 - nk;
    int t2 = t + 2 < nk ? t + 2 : t + 2 - nk;
    // ---- P1: quad (0,0); 12 ds_reads
    readA(c, 0);
    readB(c, 0, b0);
    stageB(t1, cn, 1);
    SBAR();
    mfma_quad<0, 0>(acc, a, b0);
    SBAR();
    // ---- P2: quad (0,1); 4 ds_reads
    readB(c, 1, b1);
    stageA(t2, c, 0);
    SBAR();
    mfma_quad<0, 1>(acc, a, b1);
    SBAR();
    // ---- P3: quad (1,1); 8 ds_reads
    readA(c, 1);
    stageB(t2, c, 0);
    SBAR();
    mfma_quad<1, 1>(acc, a, b1);
    SBAR();
    // ---- P4: quad (1,0); register-only, counted vmcnt once per K-tile
    stageA(t2, c, 1);
    asm volatile("s_waitcnt vmcnt(6)" ::: "memory");
    SBAR();
    mfma_quad<1, 0>(acc, a, b0);
    SBAR();
  }
  asm volatile("s_waitcnt vmcnt(0)" ::: "memory");

  // epilogue
#pragma unroll
  for (int m = 0; m < 8; ++m) {
#pragma unroll
    for (int n = 0; n < 4; ++n) {
      long rgb = (long)bm * 256 + wr * 128 + m * 16 + lg * 4;
      long cg = (long)bn * 256 + wc * 64 + n * 16 + cl;
#pragma unroll
      for (int j = 0; j < 4; ++j) {
        long r = rgb + j;
        float v = acc[m][n][j];
        if (EPI == 0) {
          ((short*)out)[r * N + cg] = f2bf(v);
        } else if (EPI == 3) {
          ((float*)out)[r * N + cg] = ((const float*)aux)[r * N + cg] + v;
        } else if (EPI == 4) {
          float gv = bf2f(((const short*)aux)[r * N + cg]);
          float sg = gv / (1.0f + __expf(-gv));
          ((short*)out)[r * N + cg] = f2bf(sg * v);
        }
      }
    }
  }
}

// ---------------- causal flash attention -----------------------------------
__global__ __launch_bounds__(512) void attn_k(const short* __restrict__ Qh,
                                              const short* __restrict__ Kh,
                                              const short* __restrict__ Vt,
                                              short* __restrict__ Ob) {
  __shared__ short Qs[128 * 128];
  __shared__ short Ks[128 * 128];
  __shared__ short Vs[128 * 128];
  __shared__ short Ps[128 * 128];
  int qt = blockIdx.x, bh = blockIdx.y;
  int t = threadIdx.x, w = t >> 6, lane = t & 63, lg = lane >> 4, c = lane & 15;
  int q0 = qt << 7;
  const short* Qb = Qh + (long)bh * SS * HDD;
  const short* Kb = Kh + (long)bh * SS * HDD;
  const short* Vb = Vt + (long)bh * HDD * SS;
#pragma unroll
  for (int i = 0; i < 4; ++i) {
    int idx = i * 512 + t;
    int row = idx >> 4, p = idx & 15;
    int col = (p ^ (row & 7)) << 3;
    GLL16(Qb + (long)(q0 + row) * HDD + col, Qs + (i * 512 + w * 64) * 8);
  }
  __syncthreads();
  short8 qf[4];
  int qrow = w * 16 + c;
#pragma unroll
  for (int kk = 0; kk < 4; ++kk)
    qf[kk] = *(const short8*)(Qs + qrow * 128 + ((((kk << 2) | lg) ^ (qrow & 7)) << 3));

  f32x4 o[8] = {};
  float mrun[4] = {-1e30f, -1e30f, -1e30f, -1e30f};
  float lrun[4] = {0.f, 0.f, 0.f, 0.f};
  const float scale = 0.08838834764831845f;
  for (int kt = 0; kt <= qt; ++kt) {
    int kv0 = kt << 7;
    __syncthreads();
#pragma unroll
    for (int i = 0; i < 4; ++i) {
      int idx = i * 512 + t;
      int row = idx >> 4, p = idx & 15;
      int col = (p ^ (row & 7)) << 3;
      GLL16(Kb + (long)(kv0 + row) * HDD + col, Ks + (i * 512 + w * 64) * 8);
      GLL16(Vb + (long)row * SS + kv0 + col, Vs + (i * 512 + w * 64) * 8);
    }
    __syncthreads();
    f32x4 sv[8];
#pragma unroll
    for (int n = 0; n < 8; ++n) {
      f32x4 acc = {};
#pragma unroll
      for (int kk = 0; kk < 4; ++kk) {
        int krow = n * 16 + c;
        short8 kf = *(const short8*)(Ks + krow * 128 + ((((kk << 2) | lg) ^ (krow & 7)) << 3));
        acc = __builtin_amdgcn_mfma_f32_16x16x32_bf16(qf[kk], kf, acc, 0, 0, 0);
      }
      sv[n] = acc;
    }
    int qg = q0 + w * 16 + lg * 4;
    if (kt == qt) {
#pragma unroll
      for (int n = 0; n < 8; ++n) {
        int col = kv0 + n * 16 + c;
#pragma unroll
        for (int j = 0; j < 4; ++j) {
          float xv = sv[n][j] * scale;
          sv[n][j] = (col > qg + j) ? -1e30f : xv;
        }
      }
    } else {
#pragma unroll
      for (int n = 0; n < 8; ++n)
#pragma unroll
        for (int j = 0; j < 4; ++j) sv[n][j] *= scale;
    }
    float alpha[4];
#pragma unroll
    for (int j = 0; j < 4; ++j) {
      float mx = sv[0][j];
#pragma unroll
      for (int n = 1; n < 8; ++n) mx = fmaxf(mx, sv[n][j]);
      mx = fmaxf(mx, __shfl_xor(mx, 1));
      mx = fmaxf(mx, __shfl_xor(mx, 2));
      mx = fmaxf(mx, __shfl_xor(mx, 4));
      mx = fmaxf(mx, __shfl_xor(mx, 8));
      float mnew = fmaxf(mrun[j], mx);
      alpha[j] = __expf(mrun[j] - mnew);
      mrun[j] = mnew;
    }
    float rsum[4] = {0.f, 0.f, 0.f, 0.f};
#pragma unroll
    for (int n = 0; n < 8; ++n)
#pragma unroll
      for (int j = 0; j < 4; ++j) {
        float p = __expf(sv[n][j] - mrun[j]);
        sv[n][j] = p;
        rsum[j] += p;
      }
#pragma unroll
    for (int j = 0; j < 4; ++j) {
      rsum[j] += __shfl_xor(rsum[j], 1);
      rsum[j] += __shfl_xor(rsum[j], 2);
      rsum[j] += __shfl_xor(rsum[j], 4);
      rsum[j] += __shfl_xor(rsum[j], 8);
      lrun[j] = lrun[j] * alpha[j] + rsum[j];
    }
#pragma unroll
    for (int n = 0; n < 8; ++n)
#pragma unroll
      for (int j = 0; j < 4; ++j) o[n][j] *= alpha[j];
#pragma unroll
    for (int n = 0; n < 8; ++n)
#pragma unroll
      for (int j = 0; j < 4; ++j) {
        int row = w * 16 + lg * 4 + j;
        int slot = (2 * n + (c >> 3)) ^ (row & 7);
        Ps[row * 128 + slot * 8 + (c & 7)] = f2bf(sv[n][j]);
      }
    __syncthreads();
    short8 pf[4];
    int prow = w * 16 + c;
#pragma unroll
    for (int kk = 0; kk < 4; ++kk)
      pf[kk] = *(const short8*)(Ps + prow * 128 + ((((kk << 2) | lg) ^ (prow & 7)) << 3));
#pragma unroll
    for (int n = 0; n < 8; ++n) {
#pragma unroll
      for (int kk = 0; kk < 4; ++kk) {
        int vrow = n * 16 + c;
        short8 vf = *(const short8*)(Vs + vrow * 128 + ((((kk << 2) | lg) ^ (vrow & 7)) << 3));
        o[n] = __builtin_amdgcn_mfma_f32_16x16x32_bf16(pf[kk], vf, o[n], 0, 0, 0);
      }
    }
  }
  int head = bh & (NHH - 1), b = bh >> 4;
#pragma unroll
  for (int j = 0; j < 4; ++j) {
    float inv = 1.0f / lrun[j];
    int s = q0 + w * 16 + lg * 4 + j;
#pragma unroll
    for (int n = 0; n < 8; ++n) {
      int hcol = head * 128 + n * 16 + c;
      Ob[((long)(b * SS + s)) * HH + hcol] = f2bf(o[n][j] * inv);
    }
  }
}

// ---------------------------------------------------------------------------
extern "C" void kernel_launch(void* const* d_in, const int* in_sizes, int n_in,
                              void* d_out, int out_size, void* d_ws, size_t ws_size,
                              hipStream_t stream) {
  (void)in_sizes; (void)n_in; (void)out_size;
  const float* x     = (const float*)d_in[0];
  const float* wq    = (const float*)d_in[2];
  const float* wk    = (const float*)d_in[3];
  const float* wv    = (const float*)d_in[4];
  const float* wo    = (const float*)d_in[5];
  const float* wgt   = (const float*)d_in[6];
  const float* wup   = (const float*)d_in[7];
  const float* wdn   = (const float*)d_in[8];
  const float* gin   = (const float*)d_in[9];
  const float* gpost = (const float*)d_in[10];
  float* out = (float*)d_out;

  const size_t R0 = 0;
  const size_t R1 = (size_t)32 << 20;
  const size_t R2 = (size_t)48 << 20;
  const size_t R3 = (size_t)112 << 20;
  const size_t NEED = (size_t)176 << 20;
  if (ws_size < NEED) return;

  short* wtq = (short*)((char*)d_ws + R0);
  short* wtk = wtq + (size_t)HH * HH;
  short* wtv = wtk + (size_t)HH * HH;
  short* wto = wtv + (size_t)HH * HH;
  short* wtd = (short*)((char*)d_ws + R0);
  short* hb  = (short*)((char*)d_ws + R1);
  short* h2  = hb;
  short* qh  = (short*)((char*)d_ws + R2);
  short* kh  = qh + (size_t)MM * HH;
  short* vt  = kh + (size_t)MM * HH;
  short* ab  = vt + (size_t)MM * HH;
  short* wtg = (short*)((char*)d_ws + R2);
  short* wtu = wtg + (size_t)HH * FF;
  short* gateb = (short*)((char*)d_ws + R3);

  dim3 b256(256, 1, 1);
  transpose_cast<<<dim3(HH / 32, HH / 32), b256, 0, stream>>>(wq, wtq, HH, HH);
  transpose_cast<<<dim3(HH / 32, HH / 32), b256, 0, stream>>>(wk, wtk, HH, HH);
  transpose_cast<<<dim3(HH / 32, HH / 32), b256, 0, stream>>>(wv, wtv, HH, HH);
  transpose_cast<<<dim3(HH / 32, HH / 32), b256, 0, stream>>>(wo, wto, HH, HH);

  rmsnorm_k<<<dim3(MM), b256, 0, stream>>>(x, gin, hb);

  dim3 gH((MM / 128) * (HH / 128), 1, 1);
  gemm_bt<1><<<gH, b256, 0, stream>>>(hb, wtq, MM, HH, HH, qh, nullptr);
  gemm_bt<1><<<gH, b256, 0, stream>>>(hb, wtk, MM, HH, HH, kh, nullptr);
  gemm_bt<2><<<gH, b256, 0, stream>>>(hb, wtv, MM, HH, HH, vt, nullptr);

  attn_k<<<dim3(SS / 128, BB * NHH), dim3(512, 1, 1), 0, stream>>>(qh, kh, vt, ab);

  gemm_bt<3><<<gH, b256, 0, stream>>>(ab, wto, MM, HH, HH, out, x);

  transpose_cast<<<dim3(FF / 32, HH / 32), b256, 0, stream>>>(wgt, wtg, HH, FF);
  transpose_cast<<<dim3(FF / 32, HH / 32), b256, 0, stream>>>(wup, wtu, HH, FF);
  transpose_cast<<<dim3(HH / 32, FF / 32), b256, 0, stream>>>(wdn, wtd, FF, HH);

  rmsnorm_k<<<dim3(MM), b256, 0, stream>>>(out, gpost, h2);

  dim3 b512(512, 1, 1);
  dim3 gF256((MM / 256) * (FF / 256), 1, 1);  // 512 WGs
  dim3 gH256((MM / 256) * (HH / 256), 1, 1);  // 128 WGs
  gemm256<0><<<gF256, b512, 0, stream>>>(h2, wtg, MM, FF, HH, gateb, nullptr);
  gemm256<4><<<gF256, b512, 0, stream>>>(h2, wtu, MM, FF, HH, gateb, gateb);
  gemm256<3><<<gH256, b512, 0, stream>>>(gateb, wtd, MM, HH, FF, out, out);
}